// Round 6
// baseline (349.150 us; speedup 1.0000x reference)
//
#include <hip/hip_runtime.h>
#include <cstdint>

#define D_MODEL 1024
#define NH 16
#define DK 64
#define SEQ 2048
#define BATCH 2
#define M_TOT (BATCH * SEQ)   // 4096

typedef __bf16 bf16x8          __attribute__((ext_vector_type(8)));
typedef unsigned short u16x8   __attribute__((ext_vector_type(8)));
typedef float  f32x4           __attribute__((ext_vector_type(4)));

union pun8 { u16x8 u; bf16x8 b; };

__device__ __forceinline__ f32x4 mfma16(bf16x8 a, bf16x8 b, f32x4 c) {
    return __builtin_amdgcn_mfma_f32_16x16x32_bf16(a, b, c, 0, 0, 0);
}

__device__ __forceinline__ unsigned short f2bf(float f) {   // RNE
    union { float f; uint32_t u; } v; v.f = f;
    uint32_t u = v.u;
    return (unsigned short)((u + 0x7FFFu + ((u >> 16) & 1u)) >> 16);
}

__device__ __forceinline__ unsigned short f2bf_trunc(float f) {  // 1-op trunc
    union { float f; uint32_t u; } v; v.f = f;
    return (unsigned short)(v.u >> 16);
}

// async global->LDS, 16 B per lane. LDS dest = wave-uniform base + lane*16.
__device__ __forceinline__ void gl_lds16(const unsigned short* g, unsigned short* l) {
    __builtin_amdgcn_global_load_lds(
        (const __attribute__((address_space(1))) void*)g,
        (__attribute__((address_space(3))) void*)l, 16, 0, 0);
}

// softmax scale folded into exp2 argument; baked into q at projection time
#define C_EXP2 0.1803368801111204f   // 0.125 * log2(e)

// ---------------------------------------------------------------------------
// One-shot fp32 -> bf16 conversion of all 7 inputs (memory-bound pre-pass).
// ---------------------------------------------------------------------------
__global__ __launch_bounds__(256) void convert_all_kernel(
    const float* __restrict__ Q,  const float* __restrict__ K,
    const float* __restrict__ V,  const float* __restrict__ Wq,
    const float* __restrict__ Wk, const float* __restrict__ Wv,
    const float* __restrict__ Wo,
    unsigned short* __restrict__ Qb,  unsigned short* __restrict__ Kb,
    unsigned short* __restrict__ Vb,  unsigned short* __restrict__ Wqb,
    unsigned short* __restrict__ Wkb, unsigned short* __restrict__ Wvb,
    unsigned short* __restrict__ Wob)
{
    int bid = blockIdx.x;
    const float* src; unsigned short* dst; int base;
    if (bid < 3 * 2048) {
        int r = bid >> 11;
        src  = (r == 0) ? Q  : (r == 1) ? K  : V;
        dst  = (r == 0) ? Qb : (r == 1) ? Kb : Vb;
        base = (bid & 2047) * 2048;
    } else {
        int u = bid - 3 * 2048;
        int r = u >> 9;
        src  = (r == 0) ? Wq  : (r == 1) ? Wk  : (r == 2) ? Wv  : Wo;
        dst  = (r == 0) ? Wqb : (r == 1) ? Wkb : (r == 2) ? Wvb : Wob;
        base = (u & 511) * 2048;
    }
    int i = base + threadIdx.x * 8;
    float4 a = *(const float4*)(src + i);
    float4 b = *(const float4*)(src + i + 4);
    u16x8 o;
    o[0] = f2bf(a.x); o[1] = f2bf(a.y); o[2] = f2bf(a.z); o[3] = f2bf(a.w);
    o[4] = f2bf(b.x); o[5] = f2bf(b.y); o[6] = f2bf(b.z); o[7] = f2bf(b.w);
    *(u16x8*)(dst + i) = o;
}

// ---------------------------------------------------------------------------
// Fused QKV projection (unchanged): q values PRE-SCALED by 0.125*log2e in the
// epilogue (z==0) so attn's per-score multiply disappears.
// z=0 -> q_scaled[B,H,S,Dk], z=1 -> k[B,H,S,Dk], z=2 -> vT[B,H,Dk,S]
// ---------------------------------------------------------------------------
__global__ __launch_bounds__(256) void qkv_proj_kernel(
    const unsigned short* __restrict__ Q,
    const unsigned short* __restrict__ K,
    const unsigned short* __restrict__ V,
    const unsigned short* __restrict__ Wq,
    const unsigned short* __restrict__ Wk,
    const unsigned short* __restrict__ Wv,
    unsigned short* __restrict__ qb,
    unsigned short* __restrict__ kb,
    unsigned short* __restrict__ vtb)
{
    const int z = blockIdx.z;
    const unsigned short* A  = (z == 0) ? Q  : (z == 1) ? K  : V;
    const unsigned short* Bt = (z == 0) ? Wq : (z == 1) ? Wk : Wv;

    const int m0 = blockIdx.y * 128;
    const int n0 = blockIdx.x * 128;

    __shared__ __align__(16) unsigned short smem[128 * 136];
    unsigned short* As = smem;
    unsigned short* Bs = smem + 128 * 64;
    unsigned short* Cs = smem;

    const int t    = threadIdx.x;
    const int lane = t & 63;
    const int w    = t >> 6;
    const int l15  = lane & 15;
    const int quad = lane >> 4;
    const int wm   = (w >> 1) * 64;
    const int wn   = (w & 1) * 64;

    f32x4 acc[4][4] = {};

    for (int k0 = 0; k0 < D_MODEL; k0 += 64) {   // 16 iterations
        __syncthreads();
        #pragma unroll
        for (int i = 0; i < 4; i++) {
            int u   = t + i * 256;
            int row = u >> 3;
            int kc  = (u & 7) * 8;
            gl_lds16(&A [(m0 + row) * D_MODEL + k0 + kc], &As[(i * 256 + w * 64) * 8]);
            gl_lds16(&Bt[(n0 + row) * D_MODEL + k0 + kc], &Bs[(i * 256 + w * 64) * 8]);
        }
        __syncthreads();

        #pragma unroll
        for (int kk = 0; kk < 2; kk++) {
            bf16x8 a[4], b[4];
            #pragma unroll
            for (int mi = 0; mi < 4; mi++)
                a[mi] = *(const bf16x8*)(&As[(wm + mi * 16 + l15) * 64 + kk * 32 + quad * 8]);
            #pragma unroll
            for (int ni = 0; ni < 4; ni++)
                b[ni] = *(const bf16x8*)(&Bs[(wn + ni * 16 + l15) * 64 + kk * 32 + quad * 8]);

            #pragma unroll
            for (int mi = 0; mi < 4; mi++)
                #pragma unroll
                for (int ni = 0; ni < 4; ni++)
                    acc[mi][ni] = mfma16(a[mi], b[ni], acc[mi][ni]);
        }
    }

    // ---- epilogue: repack through LDS, then coalesced 16B stores
    const float oscale = (z == 0) ? C_EXP2 : 1.0f;   // fold softmax scale into q
    __syncthreads();
    #pragma unroll
    for (int mi = 0; mi < 4; mi++) {
        #pragma unroll
        for (int ni = 0; ni < 4; ni++) {
            #pragma unroll
            for (int r = 0; r < 4; r++) {
                int rloc = wm + mi * 16 + quad * 4 + r;
                int cloc = wn + ni * 16 + l15;
                int rr = (z == 2) ? cloc : rloc;
                int cc = (z == 2) ? rloc : cloc;
                Cs[rr * 136 + cc] = f2bf(acc[mi][ni][r] * oscale);
            }
        }
    }
    __syncthreads();
    #pragma unroll
    for (int i = 0; i < 8; i++) {
        int u    = t + i * 256;
        int rrow = u >> 4;
        int cc8  = (u & 15) * 8;
        u16x8 val = *(const u16x8*)(&Cs[rrow * 136 + cc8]);
        unsigned short* dst;
        if (z < 2) {
            int m = m0 + rrow, n = n0 + cc8;
            int bi = m >> 11, s = m & (SEQ - 1);
            int hh = n >> 6,  d = n & (DK - 1);
            dst = ((z == 0) ? qb : kb) + (((size_t)(bi * NH + hh) * SEQ + s) * DK + d);
        } else {
            int dglob = n0 + rrow;
            int bi = m0 >> 11, s = (m0 & (SEQ - 1)) + cc8;
            int hh = dglob >> 6, d = dglob & (DK - 1);
            dst = vtb + (((size_t)(bi * NH + hh) * DK + d) * SEQ + s);
        }
        *(u16x8*)dst = val;
    }
}

// ---------------------------------------------------------------------------
// Flash attention (round 21): split-KV INSIDE the block -> 4 waves/SIMD.
//  Post-mortems R16-R20: no pipe saturated (MFMA 21 / VALU 40 / LDS ~35%);
//  kernel is TLP-starved at the structural 2 waves/SIMD (2048 waves total).
//  Fix: 512-thr blocks = 2 wave-groups x 4 waves. Group g processes kv-half
//  g (own Ks/Vs, KVBLK=64), same 128 q-rows; partials combined through LDS
//  at the end (no workspace, no extra kernel, same global traffic).
//  Grid stays 512 -> 2 blocks x 8 waves = 16 waves/CU = 4 waves/SIMD.
//  Per-wave inner loop = proven R15 shape (32 q-rows, p_lds roundtrip).
//  Row pitch 68 shorts (136B = 34 banks): kf/vf/stage conflicts 8->4-way,
//  p-writes 2-way. LDS 68 KB (2 blocks = 139 KB). launch_bounds(512,4)
//  pins VGPR <= 128 (est. ~115 peak live).
// ---------------------------------------------------------------------------
__global__ __launch_bounds__(512, 4) void attn_kernel(
    const unsigned short* __restrict__ qb,
    const unsigned short* __restrict__ kb,
    const unsigned short* __restrict__ vtb,
    unsigned short* __restrict__ ctx)
{
    const int h  = blockIdx.x;  // 0..15  (h fastest -> XCD spread across heads)
    const int qt = blockIdx.y;  // 0..15 (128 rows each)
    const int b  = blockIdx.z;  // 0..1

    const int t    = threadIdx.x;
    const int lane = t & 63;
    const int w    = t >> 6;     // 0..7
    const int g    = w >> 2;     // kv half 0/1
    const int wq   = w & 3;      // q sub-tile 0..3
    const int l15  = lane & 15;
    const int quad = lane >> 4;
    const int tl   = t & 255;    // thread index within group

    const unsigned short* qh = qb  + ((b * NH + h) * SEQ) * DK;
    const unsigned short* kh = kb  + ((b * NH + h) * SEQ) * DK;
    const unsigned short* vh = vtb + ((b * NH + h) * DK) * SEQ;

    // 68 KB: [Ks0|Ks1|Vs0|Vs1] (17408 shorts) + [P w0..w7] (17408 shorts)
    __shared__ __align__(16) unsigned short smem[34816];
    unsigned short* Ks = smem + g * 4352;           // [64][68]
    unsigned short* Vs = smem + 8704 + g * 4352;    // [64][68]
    unsigned short* Pw = smem + 17408 + w * 2176;   // [32][68]
    float* o_comb = (float*)smem;                   // overlay [128][64] (32 KB)
    float* l_comb = (float*)(smem + 17408);         // overlay [128]

    const int qrow0 = qt * 128 + wq * 32;
    bf16x8 qa[2][2];
    #pragma unroll
    for (int m = 0; m < 2; m++)
        #pragma unroll
        for (int kk = 0; kk < 2; kk++)
            qa[m][kk] = *(const bf16x8*)(&qh[(qrow0 + m * 16 + l15) * DK + kk * 32 + quad * 8]);

    pun8 ones_p;
    #pragma unroll
    for (int i = 0; i < 8; i++) ones_p.u[i] = 0x3F80;  // bf16 1.0
    const bf16x8 ones = ones_p.b;

    f32x4 o[2][4] = {};
    f32x4 lacc[2] = {};

    for (int kt = 0; kt < 16; kt++) {        // 16 x 64 kv per group
        const int c64 = (g * 16 + kt) * 64;  // this group's kv base
        __syncthreads();
        #pragma unroll
        for (int i = 0; i < 2; i++) {
            int u   = tl + i * 256;          // 0..511
            int row = u >> 3;                // 0..63
            int c8  = (u & 7) * 8;
            *(u16x8*)(&Ks[row * 68 + c8]) =
                *(const u16x8*)(&kh[(c64 + row) * DK + c8]);
        }
        #pragma unroll
        for (int i = 0; i < 2; i++) {
            int u   = tl + i * 256;
            int row = u >> 3;                // d: 0..63
            int c8  = (u & 7) * 8;           // s-offset
            *(u16x8*)(&Vs[row * 68 + c8]) =
                *(const u16x8*)(&vh[row * SEQ + c64 + c8]);
        }
        __syncthreads();

        bf16x8 kf[4][2];
        #pragma unroll
        for (int nb = 0; nb < 4; nb++) {
            kf[nb][0] = *(const bf16x8*)(&Ks[(nb * 16 + l15) * 68 + quad * 8]);
            kf[nb][1] = *(const bf16x8*)(&Ks[(nb * 16 + l15) * 68 + 32 + quad * 8]);
        }

        f32x4 sacc[2][4] = {};
        __builtin_amdgcn_s_setprio(1);
        #pragma unroll
        for (int m = 0; m < 2; m++)
            #pragma unroll
            for (int nb = 0; nb < 4; nb++) {
                sacc[m][nb] = mfma16(qa[m][0], kf[nb][0], sacc[m][nb]);
                sacc[m][nb] = mfma16(qa[m][1], kf[nb][1], sacc[m][nb]);
            }
        __builtin_amdgcn_s_setprio(0);

        // p = exp2(sacc)  — scale already baked into q at projection
        #pragma unroll
        for (int m = 0; m < 2; m++)
            #pragma unroll
            for (int nb = 0; nb < 4; nb++)
                #pragma unroll
                for (int r = 0; r < 4; r++) {
                    float p = exp2f(sacc[m][nb][r]);
                    Pw[(m * 16 + quad * 4 + r) * 68 + nb * 16 + l15] = f2bf_trunc(p);
                }

        asm volatile("" ::: "memory");  // P writes before P reads (wave-private)

        bf16x8 pa[2][2];
        #pragma unroll
        for (int m = 0; m < 2; m++)
            #pragma unroll
            for (int kk = 0; kk < 2; kk++)
                pa[m][kk] = *(const bf16x8*)(&Pw[(m * 16 + l15) * 68 + kk * 32 + quad * 8]);

        asm volatile("" ::: "memory");  // P reads before next iter's writes

        bf16x8 vf[4][2];
        #pragma unroll
        for (int db = 0; db < 4; db++) {
            vf[db][0] = *(const bf16x8*)(&Vs[(db * 16 + l15) * 68 + quad * 8]);
            vf[db][1] = *(const bf16x8*)(&Vs[(db * 16 + l15) * 68 + 32 + quad * 8]);
        }

        __builtin_amdgcn_s_setprio(1);
        #pragma unroll
        for (int db = 0; db < 4; db++)
            #pragma unroll
            for (int m = 0; m < 2; m++) {
                o[m][db] = mfma16(pa[m][0], vf[db][0], o[m][db]);
                o[m][db] = mfma16(pa[m][1], vf[db][1], o[m][db]);
            }
        #pragma unroll
        for (int m = 0; m < 2; m++) {
            lacc[m] = mfma16(pa[m][0], ones, lacc[m]);
            lacc[m] = mfma16(pa[m][1], ones, lacc[m]);
        }
        __builtin_amdgcn_s_setprio(0);
    }

    // ---- combine the two kv-halves through LDS (overlay on dead K/V tiles)
    __syncthreads();
    if (g == 1) {
        #pragma unroll
        for (int m = 0; m < 2; m++) {
            #pragma unroll
            for (int db = 0; db < 4; db++)
                #pragma unroll
                for (int r = 0; r < 4; r++)
                    o_comb[(wq * 32 + m * 16 + quad * 4 + r) * 64 + db * 16 + l15] =
                        o[m][db][r];
            if (l15 == 0) {
                #pragma unroll
                for (int r = 0; r < 4; r++)
                    l_comb[wq * 32 + m * 16 + quad * 4 + r] = lacc[m][r];
            }
        }
    }
    __syncthreads();
    if (g == 0) {
        #pragma unroll
        for (int m = 0; m < 2; m++) {
            #pragma unroll
            for (int db = 0; db < 4; db++)
                #pragma unroll
                for (int r = 0; r < 4; r++) {
                    const int row_l = wq * 32 + m * 16 + quad * 4 + r;
                    float val = (o[m][db][r] + o_comb[row_l * 64 + db * 16 + l15]) /
                                (lacc[m][r] + l_comb[row_l]);
                    ctx[(b * SEQ + qt * 128 + row_l) * D_MODEL + h * DK + db * 16 + l15] =
                        f2bf(val);
                }
        }
    }
}

// ---------------------------------------------------------------------------
// Output projection (unchanged): 64x128 tiles, BK=64.
// ---------------------------------------------------------------------------
__global__ __launch_bounds__(256) void out_proj_kernel(
    const unsigned short* __restrict__ A,
    const unsigned short* __restrict__ Bt,
    float* __restrict__ out)
{
    const int m0 = blockIdx.y * 64;
    const int n0 = blockIdx.x * 128;

    __shared__ __align__(16) unsigned short As[64 * 64];    // 8 KB
    __shared__ __align__(16) unsigned short Bs[128 * 64];   // 16 KB

    const int t    = threadIdx.x;
    const int lane = t & 63;
    const int w    = t >> 6;
    const int l15  = lane & 15;
    const int quad = lane >> 4;
    const int wn   = w * 32;

    f32x4 acc[4][2] = {};

    for (int k0 = 0; k0 < D_MODEL; k0 += 64) {   // 16 iterations
        __syncthreads();
        #pragma unroll
        for (int i = 0; i < 2; i++) {
            int u   = t + i * 256;
            int row = u >> 3;
            int kc  = (u & 7) * 8;
            gl_lds16(&A[(m0 + row) * D_MODEL + k0 + kc], &As[(i * 256 + w * 64) * 8]);
        }
        #pragma unroll
        for (int i = 0; i < 4; i++) {
            int u   = t + i * 256;
            int row = u >> 3;
            int kc  = (u & 7) * 8;
            gl_lds16(&Bt[(n0 + row) * D_MODEL + k0 + kc], &Bs[(i * 256 + w * 64) * 8]);
        }
        __syncthreads();

        #pragma unroll
        for (int kk = 0; kk < 2; kk++) {
            bf16x8 a[4], bfr[2];
            #pragma unroll
            for (int mi = 0; mi < 4; mi++)
                a[mi] = *(const bf16x8*)(&As[(mi * 16 + l15) * 64 + kk * 32 + quad * 8]);
            #pragma unroll
            for (int ni = 0; ni < 2; ni++)
                bfr[ni] = *(const bf16x8*)(&Bs[(wn + ni * 16 + l15) * 64 + kk * 32 + quad * 8]);

            #pragma unroll
            for (int mi = 0; mi < 4; mi++)
                #pragma unroll
                for (int ni = 0; ni < 2; ni++)
                    acc[mi][ni] = mfma16(a[mi], bfr[ni], acc[mi][ni]);
        }
    }

    #pragma unroll
    for (int mi = 0; mi < 4; mi++) {
        #pragma unroll
        for (int ni = 0; ni < 2; ni++) {
            #pragma unroll
            for (int r = 0; r < 4; r++) {
                int m = m0 + mi * 16 + quad * 4 + r;
                int n = n0 + wn + ni * 16 + l15;
                out[m * D_MODEL + n] = acc[mi][ni][r];
            }
        }
    }
}

extern "C" void kernel_launch(void* const* d_in, const int* in_sizes, int n_in,
                              void* d_out, int out_size, void* d_ws, size_t ws_size,
                              hipStream_t stream) {
    const float* Q  = (const float*)d_in[0];
    const float* K  = (const float*)d_in[1];
    const float* V  = (const float*)d_in[2];
    const float* Wq = (const float*)d_in[3];
    const float* Wk = (const float*)d_in[4];
    const float* Wv = (const float*)d_in[5];
    const float* Wo = (const float*)d_in[6];

    const size_t NQ = (size_t)M_TOT * D_MODEL;     // 4 Mi elements
    const size_t NW = (size_t)D_MODEL * D_MODEL;   // 1 Mi elements

    unsigned short* Qb  = (unsigned short*)d_ws;   // bf16 input copies
    unsigned short* Kb  = Qb  + NQ;
    unsigned short* Vb  = Kb  + NQ;
    unsigned short* Wqb = Vb  + NQ;
    unsigned short* Wkb = Wqb + NW;
    unsigned short* Wvb = Wkb + NW;
    unsigned short* Wob = Wvb + NW;
    unsigned short* qb  = Wob + NW;                // [B,H,S,Dk] (pre-scaled)
    unsigned short* kbf = qb  + NQ;                // [B,H,S,Dk]
    unsigned short* vtb = kbf + NQ;                // [B,H,Dk,S]
    unsigned short* ctx = vtb + NQ;                // [B*S, D]
    float* out = (float*)d_out;

    convert_all_kernel<<<3 * 2048 + 4 * 512, 256, 0, stream>>>(
        Q, K, V, Wq, Wk, Wv, Wo, Qb, Kb, Vb, Wqb, Wkb, Wvb, Wob);

    dim3 g1(D_MODEL / 128, M_TOT / 128, 3);
    qkv_proj_kernel<<<g1, 256, 0, stream>>>(Qb, Kb, Vb, Wqb, Wkb, Wvb, qb, kbf, vtb);

    dim3 g2(NH, SEQ / 128, BATCH);   // h fastest (XCD swizzle)
    attn_kernel<<<g2, 512, 0, stream>>>(qb, kbf, vtb, ctx);

    dim3 g3(D_MODEL / 128, M_TOT / 64, 1);
    out_proj_kernel<<<g3, 256, 0, stream>>>(ctx, Wob, out);
}

// Round 7
// 260.136 us; speedup vs baseline: 1.3422x; 1.3422x over previous
//
#include <hip/hip_runtime.h>
#include <cstdint>

#define D_MODEL 1024
#define NH 16
#define DK 64
#define SEQ 2048
#define BATCH 2
#define M_TOT (BATCH * SEQ)   // 4096

typedef __bf16 bf16x8          __attribute__((ext_vector_type(8)));
typedef unsigned short u16x8   __attribute__((ext_vector_type(8)));
typedef float  f32x4           __attribute__((ext_vector_type(4)));

union pun8 { u16x8 u; bf16x8 b; };

__device__ __forceinline__ f32x4 mfma16(bf16x8 a, bf16x8 b, f32x4 c) {
    return __builtin_amdgcn_mfma_f32_16x16x32_bf16(a, b, c, 0, 0, 0);
}

__device__ __forceinline__ unsigned short f2bf(float f) {   // RNE
    union { float f; uint32_t u; } v; v.f = f;
    uint32_t u = v.u;
    return (unsigned short)((u + 0x7FFFu + ((u >> 16) & 1u)) >> 16);
}

__device__ __forceinline__ unsigned short f2bf_trunc(float f) {  // 1-op trunc
    union { float f; uint32_t u; } v; v.f = f;
    return (unsigned short)(v.u >> 16);
}

__device__ __forceinline__ float bf2f(unsigned short s) {
    union { uint32_t u; float f; } v; v.u = ((uint32_t)s) << 16;
    return v.f;
}

// async global->LDS, 16 B per lane. LDS dest = wave-uniform base + lane*16.
__device__ __forceinline__ void gl_lds16(const unsigned short* g, unsigned short* l) {
    __builtin_amdgcn_global_load_lds(
        (const __attribute__((address_space(1))) void*)g,
        (__attribute__((address_space(3))) void*)l, 16, 0, 0);
}

// softmax scale folded into exp2 argument; baked into q at projection time
#define C_EXP2 0.1803368801111204f   // 0.125 * log2(e)

// ---------------------------------------------------------------------------
// One-shot fp32 -> bf16 conversion of all 7 inputs (memory-bound pre-pass).
// ---------------------------------------------------------------------------
__global__ __launch_bounds__(256) void convert_all_kernel(
    const float* __restrict__ Q,  const float* __restrict__ K,
    const float* __restrict__ V,  const float* __restrict__ Wq,
    const float* __restrict__ Wk, const float* __restrict__ Wv,
    const float* __restrict__ Wo,
    unsigned short* __restrict__ Qb,  unsigned short* __restrict__ Kb,
    unsigned short* __restrict__ Vb,  unsigned short* __restrict__ Wqb,
    unsigned short* __restrict__ Wkb, unsigned short* __restrict__ Wvb,
    unsigned short* __restrict__ Wob)
{
    int bid = blockIdx.x;
    const float* src; unsigned short* dst; int base;
    if (bid < 3 * 2048) {
        int r = bid >> 11;
        src  = (r == 0) ? Q  : (r == 1) ? K  : V;
        dst  = (r == 0) ? Qb : (r == 1) ? Kb : Vb;
        base = (bid & 2047) * 2048;
    } else {
        int u = bid - 3 * 2048;
        int r = u >> 9;
        src  = (r == 0) ? Wq  : (r == 1) ? Wk  : (r == 2) ? Wv  : Wo;
        dst  = (r == 0) ? Wqb : (r == 1) ? Wkb : (r == 2) ? Wvb : Wob;
        base = (u & 511) * 2048;
    }
    int i = base + threadIdx.x * 8;
    float4 a = *(const float4*)(src + i);
    float4 b = *(const float4*)(src + i + 4);
    u16x8 o;
    o[0] = f2bf(a.x); o[1] = f2bf(a.y); o[2] = f2bf(a.z); o[3] = f2bf(a.w);
    o[4] = f2bf(b.x); o[5] = f2bf(b.y); o[6] = f2bf(b.z); o[7] = f2bf(b.w);
    *(u16x8*)(dst + i) = o;
}

// ---------------------------------------------------------------------------
// Fused QKV projection (unchanged): q values PRE-SCALED by 0.125*log2e in the
// epilogue (z==0) so attn's per-score multiply disappears.
// z=0 -> q_scaled[B,H,S,Dk], z=1 -> k[B,H,S,Dk], z=2 -> vT[B,H,Dk,S]
// ---------------------------------------------------------------------------
__global__ __launch_bounds__(256) void qkv_proj_kernel(
    const unsigned short* __restrict__ Q,
    const unsigned short* __restrict__ K,
    const unsigned short* __restrict__ V,
    const unsigned short* __restrict__ Wq,
    const unsigned short* __restrict__ Wk,
    const unsigned short* __restrict__ Wv,
    unsigned short* __restrict__ qb,
    unsigned short* __restrict__ kb,
    unsigned short* __restrict__ vtb)
{
    const int z = blockIdx.z;
    const unsigned short* A  = (z == 0) ? Q  : (z == 1) ? K  : V;
    const unsigned short* Bt = (z == 0) ? Wq : (z == 1) ? Wk : Wv;

    const int m0 = blockIdx.y * 128;
    const int n0 = blockIdx.x * 128;

    __shared__ __align__(16) unsigned short smem[128 * 136];
    unsigned short* As = smem;
    unsigned short* Bs = smem + 128 * 64;
    unsigned short* Cs = smem;

    const int t    = threadIdx.x;
    const int lane = t & 63;
    const int w    = t >> 6;
    const int l15  = lane & 15;
    const int quad = lane >> 4;
    const int wm   = (w >> 1) * 64;
    const int wn   = (w & 1) * 64;

    f32x4 acc[4][4] = {};

    for (int k0 = 0; k0 < D_MODEL; k0 += 64) {   // 16 iterations
        __syncthreads();
        #pragma unroll
        for (int i = 0; i < 4; i++) {
            int u   = t + i * 256;
            int row = u >> 3;
            int kc  = (u & 7) * 8;
            gl_lds16(&A [(m0 + row) * D_MODEL + k0 + kc], &As[(i * 256 + w * 64) * 8]);
            gl_lds16(&Bt[(n0 + row) * D_MODEL + k0 + kc], &Bs[(i * 256 + w * 64) * 8]);
        }
        __syncthreads();

        #pragma unroll
        for (int kk = 0; kk < 2; kk++) {
            bf16x8 a[4], b[4];
            #pragma unroll
            for (int mi = 0; mi < 4; mi++)
                a[mi] = *(const bf16x8*)(&As[(wm + mi * 16 + l15) * 64 + kk * 32 + quad * 8]);
            #pragma unroll
            for (int ni = 0; ni < 4; ni++)
                b[ni] = *(const bf16x8*)(&Bs[(wn + ni * 16 + l15) * 64 + kk * 32 + quad * 8]);

            #pragma unroll
            for (int mi = 0; mi < 4; mi++)
                #pragma unroll
                for (int ni = 0; ni < 4; ni++)
                    acc[mi][ni] = mfma16(a[mi], b[ni], acc[mi][ni]);
        }
    }

    // ---- epilogue: repack through LDS, then coalesced 16B stores
    const float oscale = (z == 0) ? C_EXP2 : 1.0f;   // fold softmax scale into q
    __syncthreads();
    #pragma unroll
    for (int mi = 0; mi < 4; mi++) {
        #pragma unroll
        for (int ni = 0; ni < 4; ni++) {
            #pragma unroll
            for (int r = 0; r < 4; r++) {
                int rloc = wm + mi * 16 + quad * 4 + r;
                int cloc = wn + ni * 16 + l15;
                int rr = (z == 2) ? cloc : rloc;
                int cc = (z == 2) ? rloc : cloc;
                Cs[rr * 136 + cc] = f2bf(acc[mi][ni][r] * oscale);
            }
        }
    }
    __syncthreads();
    #pragma unroll
    for (int i = 0; i < 8; i++) {
        int u    = t + i * 256;
        int rrow = u >> 4;
        int cc8  = (u & 15) * 8;
        u16x8 val = *(const u16x8*)(&Cs[rrow * 136 + cc8]);
        unsigned short* dst;
        if (z < 2) {
            int m = m0 + rrow, n = n0 + cc8;
            int bi = m >> 11, s = m & (SEQ - 1);
            int hh = n >> 6,  d = n & (DK - 1);
            dst = ((z == 0) ? qb : kb) + (((size_t)(bi * NH + hh) * SEQ + s) * DK + d);
        } else {
            int dglob = n0 + rrow;
            int bi = m0 >> 11, s = (m0 & (SEQ - 1)) + cc8;
            int hh = dglob >> 6, d = dglob & (DK - 1);
            dst = vtb + (((size_t)(bi * NH + hh) * DK + d) * SEQ + s);
        }
        *(u16x8*)dst = val;
    }
}

// ---------------------------------------------------------------------------
// Flash attention (round 22): kv-split across BLOCKS -> 4 blocks/CU.
//  R21 post-mortem: 512-thr + launch_bounds(512,4) clamped VGPR to 64 ->
//  spill catastrophe. This round keeps the proven R19 inner loop per wave
//  (256 thr, 32 q-rows/wave, p_lds roundtrip, pipelined PV, VGPR~116) and
//  splits kv across TWO blocks (KVBLK=64, 16 steps each):
//   grid 1024 = 4 blocks/CU; LDS 36.9KB -> 4 fit; 116 VGPR x 16 waves =
//   464 <= 512/SIMD -> 4 waves/SIMD, no spill, per-unit-work traffic
//   unchanged (R17's LDS-amplification mistake avoided).
//  Each block writes normalized partial u_g = o_g/l_g (bf16, well-scaled)
//  + l_g (f32) into workspace dead after qkv; out_proj blends
//  (l0*u0 + l1*u1)/(l0+l1) during its A-staging. No ctx, no extra kernel.
// ---------------------------------------------------------------------------
__global__ __launch_bounds__(256, 2) void attn_kernel(
    const unsigned short* __restrict__ qb,
    const unsigned short* __restrict__ kb,
    const unsigned short* __restrict__ vtb,
    unsigned short* __restrict__ u0,
    unsigned short* __restrict__ u1,
    float* __restrict__ l0,
    float* __restrict__ l1)
{
    const int h  = blockIdx.x;  // 0..15  (h fastest -> XCD spread across heads)
    const int qt = blockIdx.y;  // 0..15 (128 rows each)
    const int zb = blockIdx.z;  // 0..3
    const int b  = zb >> 1;
    const int g  = zb & 1;      // kv half

    const int t    = threadIdx.x;
    const int lane = t & 63;
    const int w    = t >> 6;
    const int l15  = lane & 15;
    const int quad = lane >> 4;

    const unsigned short* qh = qb  + ((size_t)(b * NH + h) * SEQ) * DK;
    const unsigned short* kh = kb  + ((size_t)(b * NH + h) * SEQ + g * (SEQ / 2)) * DK;
    const unsigned short* vh = vtb + ((size_t)(b * NH + h) * DK) * SEQ + g * (SEQ / 2);

    __shared__ __align__(16) unsigned short p_lds[4][32][72];  // 18.0 KB
    __shared__ __align__(16) unsigned short Ks[64 * 72];       //  9.0 KB
    __shared__ __align__(16) unsigned short Vs[64 * 72];       //  9.0 KB

    const int qrow0 = qt * 128 + w * 32;
    bf16x8 qa[2][2];
    #pragma unroll
    for (int m = 0; m < 2; m++)
        #pragma unroll
        for (int kk = 0; kk < 2; kk++)
            qa[m][kk] = *(const bf16x8*)(&qh[(qrow0 + m * 16 + l15) * DK + kk * 32 + quad * 8]);

    pun8 ones_p;
    #pragma unroll
    for (int i = 0; i < 8; i++) ones_p.u[i] = 0x3F80;  // bf16 1.0
    const bf16x8 ones = ones_p.b;

    f32x4 o[2][4] = {};
    f32x4 lacc[2] = {};

    // one-iteration-delayed PV state (zero-init: first PV adds nothing)
    bf16x8 pa_p[2][2] = {};
    bf16x8 vf_p[4][2] = {};

    for (int kt = 0; kt < 16; kt++) {            // 16 x 64 kv
        __syncthreads();
        #pragma unroll
        for (int i = 0; i < 2; i++) {
            int u   = t + i * 256;       // 0..511
            int row = u >> 3;            // 0..63
            int c8  = (u & 7) * 8;
            *(u16x8*)(&Ks[row * 72 + c8]) =
                *(const u16x8*)(&kh[(kt * 64 + row) * DK + c8]);
        }
        #pragma unroll
        for (int i = 0; i < 2; i++) {
            int u   = t + i * 256;
            int row = u >> 3;            // d: 0..63
            int c8  = (u & 7) * 8;       // s-offset 0..56
            *(u16x8*)(&Vs[row * 72 + c8]) =
                *(const u16x8*)(&vh[row * SEQ + kt * 64 + c8]);
        }
        __syncthreads();

        // K fragments for current iteration
        bf16x8 kf[4][2];
        #pragma unroll
        for (int nb = 0; nb < 4; nb++) {
            const int krow = nb * 16 + l15;
            kf[nb][0] = *(const bf16x8*)(&Ks[krow * 72 + quad * 8]);
            kf[nb][1] = *(const bf16x8*)(&Ks[krow * 72 + 32 + quad * 8]);
        }

        // QK for current iteration
        f32x4 sacc[2][4] = {};
        __builtin_amdgcn_s_setprio(1);
        #pragma unroll
        for (int m = 0; m < 2; m++)
            #pragma unroll
            for (int nb = 0; nb < 4; nb++) {
                sacc[m][nb] = mfma16(qa[m][0], kf[nb][0], sacc[m][nb]);
                sacc[m][nb] = mfma16(qa[m][1], kf[nb][1], sacc[m][nb]);
            }
        __builtin_amdgcn_s_setprio(0);

        // V fragments for current iteration
        bf16x8 vf_c[4][2];
        #pragma unroll
        for (int db = 0; db < 4; db++) {
            vf_c[db][0] = *(const bf16x8*)(&Vs[(db * 16 + l15) * 72 + quad * 8]);
            vf_c[db][1] = *(const bf16x8*)(&Vs[(db * 16 + l15) * 72 + 32 + quad * 8]);
        }

        // PV for PREVIOUS iteration — pure-register MFMA on the matrix pipe
        __builtin_amdgcn_s_setprio(1);
        #pragma unroll
        for (int db = 0; db < 4; db++)
            #pragma unroll
            for (int m = 0; m < 2; m++) {
                o[m][db] = mfma16(pa_p[m][0], vf_p[db][0], o[m][db]);
                o[m][db] = mfma16(pa_p[m][1], vf_p[db][1], o[m][db]);
            }
        #pragma unroll
        for (int m = 0; m < 2; m++) {
            lacc[m] = mfma16(pa_p[m][0], ones, lacc[m]);
            lacc[m] = mfma16(pa_p[m][1], ones, lacc[m]);
        }
        __builtin_amdgcn_s_setprio(0);

        // softmax for current iteration: p = exp2(sacc)
        #pragma unroll
        for (int m = 0; m < 2; m++)
            #pragma unroll
            for (int nb = 0; nb < 4; nb++)
                #pragma unroll
                for (int r = 0; r < 4; r++) {
                    float p = exp2f(sacc[m][nb][r]);
                    p_lds[w][m * 16 + quad * 4 + r][nb * 16 + l15] = f2bf_trunc(p);
                }

        asm volatile("" ::: "memory");  // P writes before P reads (wave-private)

        #pragma unroll
        for (int m = 0; m < 2; m++)
            #pragma unroll
            for (int kk = 0; kk < 2; kk++)
                pa_p[m][kk] = *(const bf16x8*)(&p_lds[w][m * 16 + l15][kk * 32 + quad * 8]);

        asm volatile("" ::: "memory");  // P reads before next iter's writes

        #pragma unroll
        for (int db = 0; db < 4; db++) {
            vf_p[db][0] = vf_c[db][0];
            vf_p[db][1] = vf_c[db][1];
        }
    }

    // drain: PV for the final iteration
    __builtin_amdgcn_s_setprio(1);
    #pragma unroll
    for (int db = 0; db < 4; db++)
        #pragma unroll
        for (int m = 0; m < 2; m++) {
            o[m][db] = mfma16(pa_p[m][0], vf_p[db][0], o[m][db]);
            o[m][db] = mfma16(pa_p[m][1], vf_p[db][1], o[m][db]);
        }
    #pragma unroll
    for (int m = 0; m < 2; m++) {
        lacc[m] = mfma16(pa_p[m][0], ones, lacc[m]);
        lacc[m] = mfma16(pa_p[m][1], ones, lacc[m]);
    }
    __builtin_amdgcn_s_setprio(0);

    // epilogue: normalized partial u_g = o/l (bf16) + l_g (f32)
    unsigned short* ug = g ? u1 : u0;
    float*          lg = g ? l1 : l0;
    #pragma unroll
    for (int m = 0; m < 2; m++) {
        const int srow = qt * 128 + w * 32 + m * 16 + quad * 4;  // local s base
        #pragma unroll
        for (int db = 0; db < 4; db++)
            #pragma unroll
            for (int r = 0; r < 4; r++) {
                float val = o[m][db][r] / lacc[m][r];
                ug[(size_t)(b * SEQ + srow + r) * D_MODEL + h * DK + db * 16 + l15] =
                    f2bf(val);
            }
        if (l15 == 0) {
            #pragma unroll
            for (int r = 0; r < 4; r++)
                lg[(size_t)(b * NH + h) * SEQ + srow + r] = lacc[m][r];
        }
    }
}

// ---------------------------------------------------------------------------
// Output projection (round 22): 64x128 tiles, BK=64; A-staging now performs
// the kv-split combine: A[m][k] = (l0*u0 + l1*u1)/(l0+l1) -> bf16 -> LDS.
// One weight pair per (row, head); k0=64 aligns with head boundaries.
// ---------------------------------------------------------------------------
__global__ __launch_bounds__(256) void out_proj_kernel(
    const unsigned short* __restrict__ u0,
    const unsigned short* __restrict__ u1,
    const float* __restrict__ l0,
    const float* __restrict__ l1,
    const unsigned short* __restrict__ Bt,
    float* __restrict__ out)
{
    const int m0 = blockIdx.y * 64;
    const int n0 = blockIdx.x * 128;

    __shared__ __align__(16) unsigned short As[64 * 64];    // 8 KB
    __shared__ __align__(16) unsigned short Bs[128 * 64];   // 16 KB

    const int t    = threadIdx.x;
    const int lane = t & 63;
    const int w    = t >> 6;
    const int l15  = lane & 15;
    const int quad = lane >> 4;
    const int wn   = w * 32;

    f32x4 acc[4][2] = {};

    for (int k0 = 0; k0 < D_MODEL; k0 += 64) {   // 16 iterations
        __syncthreads();
        // A: combine-stage (reg-stage with per-row softmax-weight blend)
        #pragma unroll
        for (int i = 0; i < 2; i++) {
            int u   = t + i * 256;       // 0..511
            int row = u >> 3;            // 0..63
            int c8  = (u & 7) * 8;       // 0..56
            int mg  = m0 + row;
            int bb  = mg >> 11, ss = mg & (SEQ - 1);
            int hh  = (k0 + c8) >> 6;    // single head per (k0,c8) since c8<64
            float la = l0[(size_t)(bb * NH + hh) * SEQ + ss];
            float lb = l1[(size_t)(bb * NH + hh) * SEQ + ss];
            float inv = 1.0f / (la + lb);
            float wa = la * inv, wb = lb * inv;
            u16x8 a0 = *(const u16x8*)(&u0[(size_t)mg * D_MODEL + k0 + c8]);
            u16x8 a1 = *(const u16x8*)(&u1[(size_t)mg * D_MODEL + k0 + c8]);
            u16x8 o8;
            #pragma unroll
            for (int j = 0; j < 8; j++)
                o8[j] = f2bf(wa * bf2f(a0[j]) + wb * bf2f(a1[j]));
            *(u16x8*)(&As[row * 64 + c8]) = o8;
        }
        // B: async global->LDS as before
        #pragma unroll
        for (int i = 0; i < 4; i++) {
            int u   = t + i * 256;
            int row = u >> 3;
            int kc  = (u & 7) * 8;
            gl_lds16(&Bt[(n0 + row) * D_MODEL + k0 + kc], &Bs[(i * 256 + w * 64) * 8]);
        }
        __syncthreads();

        #pragma unroll
        for (int kk = 0; kk < 2; kk++) {
            bf16x8 a[4], bfr[2];
            #pragma unroll
            for (int mi = 0; mi < 4; mi++)
                a[mi] = *(const bf16x8*)(&As[(mi * 16 + l15) * 64 + kk * 32 + quad * 8]);
            #pragma unroll
            for (int ni = 0; ni < 2; ni++)
                bfr[ni] = *(const bf16x8*)(&Bs[(wn + ni * 16 + l15) * 64 + kk * 32 + quad * 8]);

            #pragma unroll
            for (int mi = 0; mi < 4; mi++)
                #pragma unroll
                for (int ni = 0; ni < 2; ni++)
                    acc[mi][ni] = mfma16(a[mi], bfr[ni], acc[mi][ni]);
        }
    }

    #pragma unroll
    for (int mi = 0; mi < 4; mi++) {
        #pragma unroll
        for (int ni = 0; ni < 2; ni++) {
            #pragma unroll
            for (int r = 0; r < 4; r++) {
                int m = m0 + mi * 16 + quad * 4 + r;
                int n = n0 + wn + ni * 16 + l15;
                out[m * D_MODEL + n] = acc[mi][ni][r];
            }
        }
    }
}

extern "C" void kernel_launch(void* const* d_in, const int* in_sizes, int n_in,
                              void* d_out, int out_size, void* d_ws, size_t ws_size,
                              hipStream_t stream) {
    const float* Q  = (const float*)d_in[0];
    const float* K  = (const float*)d_in[1];
    const float* V  = (const float*)d_in[2];
    const float* Wq = (const float*)d_in[3];
    const float* Wk = (const float*)d_in[4];
    const float* Wv = (const float*)d_in[5];
    const float* Wo = (const float*)d_in[6];

    const size_t NQ = (size_t)M_TOT * D_MODEL;     // 4 Mi elements
    const size_t NW = (size_t)D_MODEL * D_MODEL;   // 1 Mi elements

    unsigned short* Qb  = (unsigned short*)d_ws;   // bf16 input copies
    unsigned short* Kb  = Qb  + NQ;
    unsigned short* Vb  = Kb  + NQ;
    unsigned short* Wqb = Vb  + NQ;
    unsigned short* Wkb = Wqb + NW;
    unsigned short* Wvb = Wkb + NW;
    unsigned short* Wob = Wvb + NW;
    unsigned short* qb  = Wob + NW;                // [B,H,S,Dk] (pre-scaled)
    unsigned short* kbf = qb  + NQ;                // [B,H,S,Dk]
    unsigned short* vtb = kbf + NQ;                // [B,H,Dk,S]
    float* out = (float*)d_out;

    // kv-split partials overlay buffers that are DEAD after qkv_proj:
    //  u0 (bf16, 8MB) @ Qb ; u1 (bf16, 8MB) @ Kb ; l0,l1 (f32, 256KB each) @ Vb
    unsigned short* u0p = Qb;
    unsigned short* u1p = Kb;
    float* l0p = (float*)Vb;
    float* l1p = (float*)(Vb + 1024 * 1024);       // +2MB into Vb's 8MB slab

    convert_all_kernel<<<3 * 2048 + 4 * 512, 256, 0, stream>>>(
        Q, K, V, Wq, Wk, Wv, Wo, Qb, Kb, Vb, Wqb, Wkb, Wvb, Wob);

    dim3 g1(D_MODEL / 128, M_TOT / 128, 3);
    qkv_proj_kernel<<<g1, 256, 0, stream>>>(Qb, Kb, Vb, Wqb, Wkb, Wvb, qb, kbf, vtb);

    dim3 g2(NH, SEQ / 128, 2 * BATCH);   // 1024 blocks = 4/CU, h fastest
    attn_kernel<<<g2, 256, 0, stream>>>(qb, kbf, vtb, u0p, u1p, l0p, l1p);

    dim3 g3(D_MODEL / 128, M_TOT / 64, 1);
    out_proj_kernel<<<g3, 256, 0, stream>>>(u0p, u1p, l0p, l1p, Wob, out);
}

// Round 8
// 229.569 us; speedup vs baseline: 1.5209x; 1.1331x over previous
//
#include <hip/hip_runtime.h>
#include <cstdint>

#define D_MODEL 1024
#define NH 16
#define DK 64
#define SEQ 2048
#define BATCH 2
#define M_TOT (BATCH * SEQ)   // 4096

typedef __bf16 bf16x8          __attribute__((ext_vector_type(8)));
typedef unsigned short u16x8   __attribute__((ext_vector_type(8)));
typedef float  f32x4           __attribute__((ext_vector_type(4)));
typedef unsigned int u32x2     __attribute__((ext_vector_type(2)));

union pun8 { u16x8 u; bf16x8 b; };

__device__ __forceinline__ f32x4 mfma16(bf16x8 a, bf16x8 b, f32x4 c) {
    return __builtin_amdgcn_mfma_f32_16x16x32_bf16(a, b, c, 0, 0, 0);
}

__device__ __forceinline__ unsigned short f2bf(float f) {   // RNE
    union { float f; uint32_t u; } v; v.f = f;
    uint32_t u = v.u;
    return (unsigned short)((u + 0x7FFFu + ((u >> 16) & 1u)) >> 16);
}

// pack two floats -> one u32 of two bf16 (trunc), lo at low 16 bits
__device__ __forceinline__ uint32_t pkbf(float lo, float hi) {
    union { float f; uint32_t u; } a, b; a.f = lo; b.f = hi;
    return (a.u >> 16) | (b.u & 0xFFFF0000u);
}

// async global->LDS, 16 B per lane. LDS dest = wave-uniform base + lane*16.
__device__ __forceinline__ void gl_lds16(const unsigned short* g, unsigned short* l) {
    __builtin_amdgcn_global_load_lds(
        (const __attribute__((address_space(1))) void*)g,
        (__attribute__((address_space(3))) void*)l, 16, 0, 0);
}

// softmax scale folded into exp2 argument; baked into q at projection time
#define C_EXP2 0.1803368801111204f   // 0.125 * log2(e)

// ---------------------------------------------------------------------------
// One-shot fp32 -> bf16 conversion of all 7 inputs (memory-bound pre-pass).
// ---------------------------------------------------------------------------
__global__ __launch_bounds__(256) void convert_all_kernel(
    const float* __restrict__ Q,  const float* __restrict__ K,
    const float* __restrict__ V,  const float* __restrict__ Wq,
    const float* __restrict__ Wk, const float* __restrict__ Wv,
    const float* __restrict__ Wo,
    unsigned short* __restrict__ Qb,  unsigned short* __restrict__ Kb,
    unsigned short* __restrict__ Vb,  unsigned short* __restrict__ Wqb,
    unsigned short* __restrict__ Wkb, unsigned short* __restrict__ Wvb,
    unsigned short* __restrict__ Wob)
{
    int bid = blockIdx.x;
    const float* src; unsigned short* dst; int base;
    if (bid < 3 * 2048) {
        int r = bid >> 11;
        src  = (r == 0) ? Q  : (r == 1) ? K  : V;
        dst  = (r == 0) ? Qb : (r == 1) ? Kb : Vb;
        base = (bid & 2047) * 2048;
    } else {
        int u = bid - 3 * 2048;
        int r = u >> 9;
        src  = (r == 0) ? Wq  : (r == 1) ? Wk  : (r == 2) ? Wv  : Wo;
        dst  = (r == 0) ? Wqb : (r == 1) ? Wkb : (r == 2) ? Wvb : Wob;
        base = (u & 511) * 2048;
    }
    int i = base + threadIdx.x * 8;
    float4 a = *(const float4*)(src + i);
    float4 b = *(const float4*)(src + i + 4);
    u16x8 o;
    o[0] = f2bf(a.x); o[1] = f2bf(a.y); o[2] = f2bf(a.z); o[3] = f2bf(a.w);
    o[4] = f2bf(b.x); o[5] = f2bf(b.y); o[6] = f2bf(b.z); o[7] = f2bf(b.w);
    *(u16x8*)(dst + i) = o;
}

// ---------------------------------------------------------------------------
// Fused QKV projection (unchanged): q values PRE-SCALED by 0.125*log2e in the
// epilogue (z==0) so attn's per-score multiply disappears.
// z=0 -> q_scaled[B,H,S,Dk], z=1 -> k[B,H,S,Dk], z=2 -> vT[B,H,Dk,S]
// ---------------------------------------------------------------------------
__global__ __launch_bounds__(256) void qkv_proj_kernel(
    const unsigned short* __restrict__ Q,
    const unsigned short* __restrict__ K,
    const unsigned short* __restrict__ V,
    const unsigned short* __restrict__ Wq,
    const unsigned short* __restrict__ Wk,
    const unsigned short* __restrict__ Wv,
    unsigned short* __restrict__ qb,
    unsigned short* __restrict__ kb,
    unsigned short* __restrict__ vtb)
{
    const int z = blockIdx.z;
    const unsigned short* A  = (z == 0) ? Q  : (z == 1) ? K  : V;
    const unsigned short* Bt = (z == 0) ? Wq : (z == 1) ? Wk : Wv;

    const int m0 = blockIdx.y * 128;
    const int n0 = blockIdx.x * 128;

    __shared__ __align__(16) unsigned short smem[128 * 136];
    unsigned short* As = smem;
    unsigned short* Bs = smem + 128 * 64;
    unsigned short* Cs = smem;

    const int t    = threadIdx.x;
    const int lane = t & 63;
    const int w    = t >> 6;
    const int l15  = lane & 15;
    const int quad = lane >> 4;
    const int wm   = (w >> 1) * 64;
    const int wn   = (w & 1) * 64;

    f32x4 acc[4][4] = {};

    for (int k0 = 0; k0 < D_MODEL; k0 += 64) {   // 16 iterations
        __syncthreads();
        #pragma unroll
        for (int i = 0; i < 4; i++) {
            int u   = t + i * 256;
            int row = u >> 3;
            int kc  = (u & 7) * 8;
            gl_lds16(&A [(m0 + row) * D_MODEL + k0 + kc], &As[(i * 256 + w * 64) * 8]);
            gl_lds16(&Bt[(n0 + row) * D_MODEL + k0 + kc], &Bs[(i * 256 + w * 64) * 8]);
        }
        __syncthreads();

        #pragma unroll
        for (int kk = 0; kk < 2; kk++) {
            bf16x8 a[4], b[4];
            #pragma unroll
            for (int mi = 0; mi < 4; mi++)
                a[mi] = *(const bf16x8*)(&As[(wm + mi * 16 + l15) * 64 + kk * 32 + quad * 8]);
            #pragma unroll
            for (int ni = 0; ni < 4; ni++)
                b[ni] = *(const bf16x8*)(&Bs[(wn + ni * 16 + l15) * 64 + kk * 32 + quad * 8]);

            #pragma unroll
            for (int mi = 0; mi < 4; mi++)
                #pragma unroll
                for (int ni = 0; ni < 4; ni++)
                    acc[mi][ni] = mfma16(a[mi], b[ni], acc[mi][ni]);
        }
    }

    // ---- epilogue: repack through LDS, then coalesced 16B stores
    const float oscale = (z == 0) ? C_EXP2 : 1.0f;   // fold softmax scale into q
    __syncthreads();
    #pragma unroll
    for (int mi = 0; mi < 4; mi++) {
        #pragma unroll
        for (int ni = 0; ni < 4; ni++) {
            #pragma unroll
            for (int r = 0; r < 4; r++) {
                int rloc = wm + mi * 16 + quad * 4 + r;
                int cloc = wn + ni * 16 + l15;
                int rr = (z == 2) ? cloc : rloc;
                int cc = (z == 2) ? rloc : cloc;
                Cs[rr * 136 + cc] = f2bf(acc[mi][ni][r] * oscale);
            }
        }
    }
    __syncthreads();
    #pragma unroll
    for (int i = 0; i < 8; i++) {
        int u    = t + i * 256;
        int rrow = u >> 4;
        int cc8  = (u & 15) * 8;
        u16x8 val = *(const u16x8*)(&Cs[rrow * 136 + cc8]);
        unsigned short* dst;
        if (z < 2) {
            int m = m0 + rrow, n = n0 + cc8;
            int bi = m >> 11, s = m & (SEQ - 1);
            int hh = n >> 6,  d = n & (DK - 1);
            dst = ((z == 0) ? qb : kb) + (((size_t)(bi * NH + hh) * SEQ + s) * DK + d);
        } else {
            int dglob = n0 + rrow;
            int bi = m0 >> 11, s = (m0 & (SEQ - 1)) + cc8;
            int hh = dglob >> 6, d = dglob & (DK - 1);
            dst = vtb + (((size_t)(bi * NH + hh) * DK + d) * SEQ + s);
        }
        *(u16x8*)dst = val;
    }
}

// ---------------------------------------------------------------------------
// Flash attention (round 23): R19 structure + swapped QK^T + b64 P-writes.
//  R22 post-mortem: 4 blocks/CU gave NO concurrency gain (occupancy stayed
//  19%, MfmaUtil 20) — the shared LDS pipe (~70% busy) is the binding
//  resource; more waves just queue on it. So reduce LDS instrs/unit-work:
//  the 64 scalar b16 P-writes per wave-kt are ~40% of DS-pipe load.
//  Fix: compute S^T = mfma(kf, qa) so each lane holds P for one q-row
//  (col=l15) with 4 CONSECUTIVE k (row=quad*4+r). exp2 -> pack 4 bf16 ->
//  ONE ds_write_b64 per (m,nb): 16 b64 writes replace 64 scalar writes.
//  pa reads (b128 from p_lds[q][k]) and ALL else identical to R19
//  (pipelined PV, setprio, staging, grid, epilogue). Unlike R16, nothing
//  moves onto the VALU critical path (no permlane).
// ---------------------------------------------------------------------------
__global__ __launch_bounds__(256, 2) void attn_kernel(
    const unsigned short* __restrict__ qb,
    const unsigned short* __restrict__ kb,
    const unsigned short* __restrict__ vtb,
    unsigned short* __restrict__ ctx)
{
    const int h  = blockIdx.x;  // 0..15  (h fastest -> XCD spread across heads)
    const int qt = blockIdx.y;  // 0..15 (128 rows each)
    const int b  = blockIdx.z;  // 0..1

    const int t    = threadIdx.x;
    const int lane = t & 63;
    const int w    = t >> 6;
    const int l15  = lane & 15;
    const int quad = lane >> 4;

    const unsigned short* qh = qb  + ((b * NH + h) * SEQ) * DK;
    const unsigned short* kh = kb  + ((b * NH + h) * SEQ) * DK;
    const unsigned short* vh = vtb + ((b * NH + h) * DK) * SEQ;

    __shared__ __align__(16) unsigned short p_lds[4][32][72];  // 18.0 KB
    __shared__ __align__(16) unsigned short Ks[128 * 72];      // 18.0 KB
    __shared__ __align__(16) unsigned short Vs[64 * 136];      // 17.0 KB

    const int qrow0 = qt * 128 + w * 32;
    bf16x8 qa[2][2];
    #pragma unroll
    for (int m = 0; m < 2; m++)
        #pragma unroll
        for (int kk = 0; kk < 2; kk++)
            qa[m][kk] = *(const bf16x8*)(&qh[(qrow0 + m * 16 + l15) * DK + kk * 32 + quad * 8]);

    pun8 ones_p;
    #pragma unroll
    for (int i = 0; i < 8; i++) ones_p.u[i] = 0x3F80;  // bf16 1.0
    const bf16x8 ones = ones_p.b;

    f32x4 o[2][4] = {};
    f32x4 lacc[2] = {};

    // one-iteration-delayed PV state (zero-init: first PV adds nothing)
    bf16x8 pa_p[2][2] = {};
    bf16x8 vf_p[4][2] = {};

    for (int kt = 0; kt < SEQ / 128; kt++) {     // 16 iterations
        __syncthreads();
        #pragma unroll
        for (int i = 0; i < 4; i++) {
            int u   = t + i * 256;       // 0..1023
            int row = u >> 3;            // 0..127
            int c8  = (u & 7) * 8;
            *(u16x8*)(&Ks[row * 72 + c8]) =
                *(const u16x8*)(&kh[(kt * 128 + row) * DK + c8]);
        }
        #pragma unroll
        for (int i = 0; i < 4; i++) {
            int u   = t + i * 256;       // 0..1023
            int row = u >> 4;            // 0..63
            int c8  = (u & 15) * 8;      // 0..120
            *(u16x8*)(&Vs[row * 136 + c8]) =
                *(const u16x8*)(&vh[row * SEQ + kt * 128 + c8]);
        }
        __syncthreads();

        #pragma unroll
        for (int hh = 0; hh < 2; hh++) {
            // K fragments for current iteration
            bf16x8 kf[4][2];
            #pragma unroll
            for (int nb = 0; nb < 4; nb++) {
                const int krow = hh * 64 + nb * 16 + l15;
                kf[nb][0] = *(const bf16x8*)(&Ks[krow * 72 + quad * 8]);
                kf[nb][1] = *(const bf16x8*)(&Ks[krow * 72 + 32 + quad * 8]);
            }

            // QK for current iteration — SWAPPED: st = K·Q^T.
            // st[m][nb][r] @lane(quad,l15): q = m*16+l15, k = nb*16+quad*4+r
            f32x4 sacc[2][4] = {};
            __builtin_amdgcn_s_setprio(1);
            #pragma unroll
            for (int m = 0; m < 2; m++)
                #pragma unroll
                for (int nb = 0; nb < 4; nb++) {
                    sacc[m][nb] = mfma16(kf[nb][0], qa[m][0], sacc[m][nb]);
                    sacc[m][nb] = mfma16(kf[nb][1], qa[m][1], sacc[m][nb]);
                }
            __builtin_amdgcn_s_setprio(0);

            // V fragments for current iteration (latency hides under PV/exp)
            bf16x8 vf_c[4][2];
            #pragma unroll
            for (int db = 0; db < 4; db++) {
                vf_c[db][0] = *(const bf16x8*)(&Vs[(db * 16 + l15) * 136 + hh * 64 + quad * 8]);
                vf_c[db][1] = *(const bf16x8*)(&Vs[(db * 16 + l15) * 136 + hh * 64 + 32 + quad * 8]);
            }

            // PV for PREVIOUS iteration — pure-register MFMA on the matrix pipe
            __builtin_amdgcn_s_setprio(1);
            #pragma unroll
            for (int db = 0; db < 4; db++)
                #pragma unroll
                for (int m = 0; m < 2; m++) {
                    o[m][db] = mfma16(pa_p[m][0], vf_p[db][0], o[m][db]);
                    o[m][db] = mfma16(pa_p[m][1], vf_p[db][1], o[m][db]);
                }
            #pragma unroll
            for (int m = 0; m < 2; m++) {
                lacc[m] = mfma16(pa_p[m][0], ones, lacc[m]);
                lacc[m] = mfma16(pa_p[m][1], ones, lacc[m]);
            }
            __builtin_amdgcn_s_setprio(0);

            // softmax: p = exp2(st); pack 4 consecutive-k bf16 -> 1 b64 write
            #pragma unroll
            for (int m = 0; m < 2; m++)
                #pragma unroll
                for (int nb = 0; nb < 4; nb++) {
                    float e0 = exp2f(sacc[m][nb][0]);
                    float e1 = exp2f(sacc[m][nb][1]);
                    float e2 = exp2f(sacc[m][nb][2]);
                    float e3 = exp2f(sacc[m][nb][3]);
                    u32x2 pw;
                    pw[0] = pkbf(e0, e1);
                    pw[1] = pkbf(e2, e3);
                    *(u32x2*)(&p_lds[w][m * 16 + l15][nb * 16 + quad * 4]) = pw;
                }

            asm volatile("" ::: "memory");  // P writes before P reads (wave-private)

            #pragma unroll
            for (int m = 0; m < 2; m++)
                #pragma unroll
                for (int kk = 0; kk < 2; kk++)
                    pa_p[m][kk] = *(const bf16x8*)(&p_lds[w][m * 16 + l15][kk * 32 + quad * 8]);

            asm volatile("" ::: "memory");  // P reads before next iter's writes

            #pragma unroll
            for (int db = 0; db < 4; db++) {
                vf_p[db][0] = vf_c[db][0];
                vf_p[db][1] = vf_c[db][1];
            }
        }
    }

    // drain: PV for the final iteration
    __builtin_amdgcn_s_setprio(1);
    #pragma unroll
    for (int db = 0; db < 4; db++)
        #pragma unroll
        for (int m = 0; m < 2; m++) {
            o[m][db] = mfma16(pa_p[m][0], vf_p[db][0], o[m][db]);
            o[m][db] = mfma16(pa_p[m][1], vf_p[db][1], o[m][db]);
        }
    #pragma unroll
    for (int m = 0; m < 2; m++) {
        lacc[m] = mfma16(pa_p[m][0], ones, lacc[m]);
        lacc[m] = mfma16(pa_p[m][1], ones, lacc[m]);
    }
    __builtin_amdgcn_s_setprio(0);

    #pragma unroll
    for (int m = 0; m < 2; m++) {
        const int srow_base = b * SEQ + qt * 128 + w * 32 + m * 16 + quad * 4;
        #pragma unroll
        for (int db = 0; db < 4; db++)
            #pragma unroll
            for (int r = 0; r < 4; r++) {
                float val = o[m][db][r] / lacc[m][r];
                ctx[(srow_base + r) * D_MODEL + h * DK + db * 16 + l15] = f2bf(val);
            }
    }
}

// ---------------------------------------------------------------------------
// Output projection (unchanged): 64x128 tiles, BK=64.
// ---------------------------------------------------------------------------
__global__ __launch_bounds__(256) void out_proj_kernel(
    const unsigned short* __restrict__ A,
    const unsigned short* __restrict__ Bt,
    float* __restrict__ out)
{
    const int m0 = blockIdx.y * 64;
    const int n0 = blockIdx.x * 128;

    __shared__ __align__(16) unsigned short As[64 * 64];    // 8 KB
    __shared__ __align__(16) unsigned short Bs[128 * 64];   // 16 KB

    const int t    = threadIdx.x;
    const int lane = t & 63;
    const int w    = t >> 6;
    const int l15  = lane & 15;
    const int quad = lane >> 4;
    const int wn   = w * 32;

    f32x4 acc[4][2] = {};

    for (int k0 = 0; k0 < D_MODEL; k0 += 64) {   // 16 iterations
        __syncthreads();
        #pragma unroll
        for (int i = 0; i < 2; i++) {
            int u   = t + i * 256;
            int row = u >> 3;
            int kc  = (u & 7) * 8;
            gl_lds16(&A[(m0 + row) * D_MODEL + k0 + kc], &As[(i * 256 + w * 64) * 8]);
        }
        #pragma unroll
        for (int i = 0; i < 4; i++) {
            int u   = t + i * 256;
            int row = u >> 3;
            int kc  = (u & 7) * 8;
            gl_lds16(&Bt[(n0 + row) * D_MODEL + k0 + kc], &Bs[(i * 256 + w * 64) * 8]);
        }
        __syncthreads();

        #pragma unroll
        for (int kk = 0; kk < 2; kk++) {
            bf16x8 a[4], bfr[2];
            #pragma unroll
            for (int mi = 0; mi < 4; mi++)
                a[mi] = *(const bf16x8*)(&As[(mi * 16 + l15) * 64 + kk * 32 + quad * 8]);
            #pragma unroll
            for (int ni = 0; ni < 2; ni++)
                bfr[ni] = *(const bf16x8*)(&Bs[(wn + ni * 16 + l15) * 64 + kk * 32 + quad * 8]);

            #pragma unroll
            for (int mi = 0; mi < 4; mi++)
                #pragma unroll
                for (int ni = 0; ni < 2; ni++)
                    acc[mi][ni] = mfma16(a[mi], bfr[ni], acc[mi][ni]);
        }
    }

    #pragma unroll
    for (int mi = 0; mi < 4; mi++) {
        #pragma unroll
        for (int ni = 0; ni < 2; ni++) {
            #pragma unroll
            for (int r = 0; r < 4; r++) {
                int m = m0 + mi * 16 + quad * 4 + r;
                int n = n0 + wn + ni * 16 + l15;
                out[m * D_MODEL + n] = acc[mi][ni][r];
            }
        }
    }
}

extern "C" void kernel_launch(void* const* d_in, const int* in_sizes, int n_in,
                              void* d_out, int out_size, void* d_ws, size_t ws_size,
                              hipStream_t stream) {
    const float* Q  = (const float*)d_in[0];
    const float* K  = (const float*)d_in[1];
    const float* V  = (const float*)d_in[2];
    const float* Wq = (const float*)d_in[3];
    const float* Wk = (const float*)d_in[4];
    const float* Wv = (const float*)d_in[5];
    const float* Wo = (const float*)d_in[6];

    const size_t NQ = (size_t)M_TOT * D_MODEL;     // 4 Mi elements
    const size_t NW = (size_t)D_MODEL * D_MODEL;   // 1 Mi elements

    unsigned short* Qb  = (unsigned short*)d_ws;   // bf16 input copies
    unsigned short* Kb  = Qb  + NQ;
    unsigned short* Vb  = Kb  + NQ;
    unsigned short* Wqb = Vb  + NQ;
    unsigned short* Wkb = Wqb + NW;
    unsigned short* Wvb = Wkb + NW;
    unsigned short* Wob = Wvb + NW;
    unsigned short* qb  = Wob + NW;                // [B,H,S,Dk] (pre-scaled)
    unsigned short* kbf = qb  + NQ;                // [B,H,S,Dk]
    unsigned short* vtb = kbf + NQ;                // [B,H,Dk,S]
    unsigned short* ctx = vtb + NQ;                // [B*S, D]
    float* out = (float*)d_out;

    convert_all_kernel<<<3 * 2048 + 4 * 512, 256, 0, stream>>>(
        Q, K, V, Wq, Wk, Wv, Wo, Qb, Kb, Vb, Wqb, Wkb, Wvb, Wob);

    dim3 g1(D_MODEL / 128, M_TOT / 128, 3);
    qkv_proj_kernel<<<g1, 256, 0, stream>>>(Qb, Kb, Vb, Wqb, Wkb, Wvb, qb, kbf, vtb);

    dim3 g2(NH, SEQ / 128, BATCH);   // h fastest (XCD swizzle)
    attn_kernel<<<g2, 256, 0, stream>>>(qb, kbf, vtb, ctx);

    dim3 g3(D_MODEL / 128, M_TOT / 64, 1);
    out_proj_kernel<<<g3, 256, 0, stream>>>(ctx, Wob, out);
}